// Round 1
// baseline (416.465 us; speedup 1.0000x reference)
//
#include <hip/hip_runtime.h>

typedef unsigned short u16;
typedef __attribute__((ext_vector_type(8))) short short8;
typedef __attribute__((ext_vector_type(4))) float f32x4;

#define BATCH   16
#define CCH     512
#define NBOX    36
#define SS      26
#define INDIM   25088   // 512*49
#define HIDN    512
#define M_ROWS  576     // BATCH*NBOX
#define KSPLIT  28
#define KITERS  14      // per split, BK=64 -> 28*14*64 = 25088

__device__ __forceinline__ u16 f2bf(float f) {
  unsigned u = __float_as_uint(f);
  u += 0x7FFF + ((u >> 16) & 1);   // RNE
  return (u16)(u >> 16);
}
__device__ __forceinline__ float bf2f(u16 h) {
  return __uint_as_float(((unsigned)h) << 16);
}

typedef __attribute__((address_space(3))) void* as3_ptr;
typedef const __attribute__((address_space(1))) void* as1_cptr;
__device__ __forceinline__ void gload_lds16(const void* g, void* l) {
  __builtin_amdgcn_global_load_lds((as1_cptr)g, (as3_ptr)l, 16, 0, 0);
}

// ---------------- kernel 1: transpose lf (B,C,H,W) f32 -> (B,HW,C) bf16 ----
__global__ __launch_bounds__(256) void k_transpose_lf(const float* __restrict__ in,
                                                      u16* __restrict__ out) {
  __shared__ float t[32][33];
  int b = blockIdx.z, ct = blockIdx.y, pt = blockIdx.x;
  int tx = threadIdx.x, ty = threadIdx.y;
#pragma unroll
  for (int i = 0; i < 4; ++i) {
    int c = ct * 32 + ty + i * 8;
    int p = pt * 32 + tx;
    t[ty + i * 8][tx] = in[((size_t)b * CCH + c) * 1024 + p];
  }
  __syncthreads();
#pragma unroll
  for (int i = 0; i < 4; ++i) {
    int p = pt * 32 + ty + i * 8;
    int c = ct * 32 + tx;
    out[((size_t)b * 1024 + p) * CCH + c] = f2bf(t[tx][ty + i * 8]);
  }
}

// ---------------- kernel 2: roi_fc_W f32 -> bf16 ---------------------------
__global__ __launch_bounds__(256) void k_convert_w(const float4* __restrict__ in,
                                                   ushort4* __restrict__ out) {
  int i = blockIdx.x * 256 + threadIdx.x;   // grid sized exactly
  float4 v = in[i];
  ushort4 o;
  o.x = f2bf(v.x); o.y = f2bf(v.y); o.z = f2bf(v.z); o.w = f2bf(v.w);
  out[i] = o;
}

// ---------------- kernel 3: ROI align -> flat (576, 25088) bf16 ------------
__global__ __launch_bounds__(512) void k_roi(const u16* __restrict__ lf_t,
                                             const float* __restrict__ pred,
                                             u16* __restrict__ flat) {
  __shared__ int   s_ylo[14], s_yhi[14], s_xlo[14], s_xhi[14];
  __shared__ float s_wyl[14], s_wyh[14], s_wxl[14], s_wxh[14];
  __shared__ u16   s_out[INDIM];   // 50176 B

  int blk = blockIdx.x;
  int b = blk / NBOX, n = blk % NBOX;
  int t = threadIdx.x;

  if (t < 28) {
    bool isY = t < 14;
    int j = isY ? t : t - 14;
    float c0, c1, c2, c3;
    if (n < SS) {
      const float* p = pred + ((size_t)(b * SS + n)) * 4;
      c0 = p[0]; c1 = p[1]; c2 = p[2]; c3 = p[3];
    } else { c0 = 0.f; c1 = 0.f; c2 = 1.f; c3 = 1.f; }
    float lo1 = (isY ? c1 : c0) * 32.f;
    float hi1 = (isY ? c3 : c2) * 32.f;
    float sz = fmaxf(hi1 - lo1, 1.f);
    float bs = sz * (1.f / 7.f);
    float off = (float)(j >> 1) + 0.25f + 0.5f * (float)(j & 1);
    float pos = lo1 + off * bs;
    bool valid = (pos > -1.f) && (pos < 32.f);
    float tc = fminf(fmaxf(pos, 0.f), 31.f);
    int lo = (int)floorf(tc);
    int hi = min(lo + 1, 31);
    float fr = tc - (float)lo;
    float wl = valid ? (1.f - fr) : 0.f;
    float wh = valid ? fr : 0.f;
    if (isY) { s_ylo[j] = lo; s_yhi[j] = hi; s_wyl[j] = wl; s_wyh[j] = wh; }
    else     { s_xlo[j] = lo; s_xhi[j] = hi; s_wxl[j] = wl; s_wxh[j] = wh; }
  }
  __syncthreads();

  int c = t;  // 512 threads == 512 channels
  const u16* base = lf_t + (size_t)b * 1024 * CCH + c;
  float acc[49];
#pragma unroll
  for (int p = 0; p < 49; ++p) acc[p] = 0.f;

#pragma unroll
  for (int jy = 0; jy < 14; ++jy) {
    const u16* rlo = base + s_ylo[jy] * 32 * CCH;
    const u16* rhi = base + s_yhi[jy] * 32 * CCH;
    float wyl = s_wyl[jy], wyh = s_wyh[jy];
#pragma unroll
    for (int jx = 0; jx < 14; ++jx) {
      int xl = s_xlo[jx] * CCH, xh = s_xhi[jx] * CCH;
      float fll = bf2f(rlo[xl]), flh = bf2f(rlo[xh]);
      float fhl = bf2f(rhi[xl]), fhh = bf2f(rhi[xh]);
      float v = s_wxl[jx] * (wyl * fll + wyh * fhl) +
                s_wxh[jx] * (wyl * flh + wyh * fhh);
      acc[(jy >> 1) * 7 + (jx >> 1)] += v;
    }
  }
#pragma unroll
  for (int p = 0; p < 49; ++p) s_out[c * 49 + p] = f2bf(acc[p] * 0.25f);
  __syncthreads();

  uint4* dst = (uint4*)(flat + (size_t)blk * INDIM);
  const uint4* src = (const uint4*)s_out;
  for (int i = t; i < INDIM / 8; i += 512) dst[i] = src[i];
}

// ---------------- kernel 4: GEMM 576(+pad)x512xK, split-K, bf16 MFMA -------
__global__ __launch_bounds__(256) void k_gemm(const u16* __restrict__ flat,
                                              const u16* __restrict__ Wb,
                                              float* __restrict__ partials) {
  __shared__ u16 As[128 * 64];
  __shared__ u16 Bs[128 * 64];

  int tid = threadIdx.x;
  int wave = tid >> 6, lane = tid & 63;
  int wm = wave >> 1, wn = wave & 1;
  int quad = lane >> 4, r = lane & 15;

  int tileM0 = blockIdx.y * 128;
  int tileN0 = blockIdx.x * 128;
  int kbase = blockIdx.z * (KITERS * 64);

  f32x4 acc[4][4];
#pragma unroll
  for (int mi = 0; mi < 4; ++mi)
#pragma unroll
    for (int ni = 0; ni < 4; ++ni) acc[mi][ni] = (f32x4){0.f, 0.f, 0.f, 0.f};

  for (int kt = 0; kt < KITERS; ++kt) {
    int k0 = kbase + kt * 64;
    // stage A and B (16B global_load_lds, lane-contiguous LDS dest)
#pragma unroll
    for (int t = 0; t < 4; ++t) {
      int chunk = (wave * 4 + t) * 64 + lane;
      int row = chunk >> 3;
      int col = (chunk & 7) << 3;
      int grow = min(tileM0 + row, M_ROWS - 1);   // clamp M tail
      gload_lds16(flat + (size_t)grow * INDIM + k0 + col,
                  &As[(wave * 4 + t) * 512]);
      int nrow = tileN0 + row;
      gload_lds16(Wb + (size_t)nrow * INDIM + k0 + col,
                  &Bs[(wave * 4 + t) * 512]);
    }
    __syncthreads();   // drains vmcnt before barrier (compiler-inserted)

#pragma unroll
    for (int kk = 0; kk < 64; kk += 32) {
      short8 af[4], bfr[4];
#pragma unroll
      for (int mi = 0; mi < 4; ++mi)
        af[mi] = *(const short8*)&As[(wm * 64 + mi * 16 + r) * 64 + kk + quad * 8];
#pragma unroll
      for (int ni = 0; ni < 4; ++ni)
        bfr[ni] = *(const short8*)&Bs[(wn * 64 + ni * 16 + r) * 64 + kk + quad * 8];
#pragma unroll
      for (int mi = 0; mi < 4; ++mi)
#pragma unroll
        for (int ni = 0; ni < 4; ++ni)
          acc[mi][ni] = __builtin_amdgcn_mfma_f32_16x16x32_bf16(
              af[mi], bfr[ni], acc[mi][ni], 0, 0, 0);
    }
    __syncthreads();
  }

  float* part = partials + (size_t)blockIdx.z * (M_ROWS * HIDN);
#pragma unroll
  for (int mi = 0; mi < 4; ++mi)
#pragma unroll
    for (int ni = 0; ni < 4; ++ni) {
      int row0 = tileM0 + wm * 64 + mi * 16 + quad * 4;
      int col = tileN0 + wn * 64 + ni * 16 + r;
#pragma unroll
      for (int reg = 0; reg < 4; ++reg) {
        int row = row0 + reg;
        if (row < M_ROWS) part[(size_t)row * HIDN + col] = acc[mi][ni][reg];
      }
    }
}

// ---------------- kernel 5: reduce split-K + bias + relu -> feats f32 ------
__global__ __launch_bounds__(256) void k_reduce(const float* __restrict__ partials,
                                                const float* __restrict__ bias,
                                                float* __restrict__ feats) {
  int gid = blockIdx.x * 256 + threadIdx.x;   // < 576*512
  int h = gid & (HIDN - 1);
  float s = 0.f;
#pragma unroll
  for (int k = 0; k < KSPLIT; ++k) s += partials[(size_t)k * (M_ROWS * HIDN) + gid];
  s += bias[h];
  feats[gid] = fmaxf(s, 0.f);
}

// ---------------- kernel 6: all heads, one wave per output dot -------------
__device__ __forceinline__ float wave_red(float s) {
#pragma unroll
  for (int off = 32; off > 0; off >>= 1) s += __shfl_down(s, off);
  return s;
}

__global__ __launch_bounds__(256) void k_heads(const float* __restrict__ feats,
                                               const float* __restrict__ pred,
                                               const float* __restrict__ cW,
                                               const float* __restrict__ cb,
                                               const float* __restrict__ pW,
                                               const float* __restrict__ pb,
                                               const float* __restrict__ lW,
                                               const float* __restrict__ lb,
                                               const float* __restrict__ gW,
                                               const float* __restrict__ gb,
                                               const int* __restrict__ lidx,
                                               const int* __restrict__ gidx,
                                               float* __restrict__ out) {
  int wid = blockIdx.x * 4 + (threadIdx.x >> 6);   // 0..4639
  int lane = threadIdx.x & 63;
  float sum = 0.f;

  if (wid < 1664) {                 // refined (B,26,4)
    int b = wid / 104, rr = wid % 104, s = rr >> 2, o = rr & 3;
    const float* f = feats + (size_t)(b * NBOX + s) * HIDN;
    const float* w = cW + (size_t)(s * 4 + o) * HIDN;
#pragma unroll
    for (int i = 0; i < 8; ++i) sum += f[lane + i * 64] * w[lane + i * 64];
    sum = wave_red(sum);
    if (lane == 0) {
      const float* p = pred + (size_t)(b * SS + s) * 4;
      float wdt = p[2] - p[0], hgt = p[3] - p[1];
      float whv = (o & 1) ? hgt : wdt;
      out[wid] = p[o] + (sum + cb[s * 4 + o]) * whv;
    }
  } else if (wid < 2080) {          // presence (B,26)
    int i = wid - 1664;
    int b = i / 26, s = i % 26;
    const float* f = feats + (size_t)(b * NBOX + s) * HIDN;
    const float* w = pW + (size_t)s * HIDN;
#pragma unroll
    for (int k = 0; k < 8; ++k) sum += f[lane + k * 64] * w[lane + k * 64];
    sum = wave_red(sum);
    if (lane == 0) out[1664 + i] = sum + pb[s];
  } else if (wid < 3616) {          // loc (B,12,8)
    int i = wid - 2080;
    int b = i / 96, rr = i % 96, l = rr >> 3, o = rr & 7;
    const float* f = feats + (size_t)(b * NBOX + lidx[l]) * HIDN;
    const float* w = lW + (size_t)(l * 8 + o) * HIDN;
#pragma unroll
    for (int k = 0; k < 8; ++k) sum += f[lane + k * 64] * w[lane + k * 64];
    sum = wave_red(sum);
    if (lane == 0) out[2080 + b * 160 + rr] = sum + lb[l * 8 + o];
  } else {                          // grp (B,4,16), K = 6*512
    int i = wid - 3616;
    int b = i / 64, rr = i % 64, g = rr >> 4, o = rr & 15;
    const float* w = gW + (size_t)(g * 16 + o) * 3072;
#pragma unroll
    for (int jj = 0; jj < 6; ++jj) {
      const float* f = feats + (size_t)(b * NBOX + gidx[g * 6 + jj]) * HIDN;
      const float* wj = w + jj * 512;
#pragma unroll
      for (int k = 0; k < 8; ++k) sum += f[lane + k * 64] * wj[lane + k * 64];
    }
    sum = wave_red(sum);
    if (lane == 0) out[2080 + b * 160 + 96 + rr] = sum + gb[g * 16 + o];
  }
}

// ---------------------------------------------------------------------------
extern "C" void kernel_launch(void* const* d_in, const int* in_sizes, int n_in,
                              void* d_out, int out_size, void* d_ws, size_t ws_size,
                              hipStream_t stream) {
  const float* lf      = (const float*)d_in[0];
  const float* pred    = (const float*)d_in[1];
  const float* roiW    = (const float*)d_in[2];
  const float* roiB    = (const float*)d_in[3];
  const float* cW      = (const float*)d_in[4];
  const float* cb      = (const float*)d_in[5];
  const float* pW      = (const float*)d_in[6];
  const float* pb      = (const float*)d_in[7];
  const float* lW      = (const float*)d_in[8];
  const float* lb      = (const float*)d_in[9];
  const float* gW      = (const float*)d_in[10];
  const float* gb      = (const float*)d_in[11];
  const int*   lidx    = (const int*)d_in[12];
  const int*   gidx    = (const int*)d_in[13];
  float* out = (float*)d_out;

  char* ws = (char*)d_ws;
  // region 0: lf_t (16.8 MB) then reused by partials (33.0 MB) after k_roi
  u16*   lf_t     = (u16*)ws;
  float* partials = (float*)ws;
  u16*   Wb   = (u16*)(ws + 33030144);                 // 25,690,112 B
  u16*   flat = (u16*)(ws + 33030144 + 25690112);      // 28,901,376 B
  float* feats = (float*)(ws + 33030144 + 25690112 + 28901376); // 1,179,648 B

  k_transpose_lf<<<dim3(32, 16, 16), dim3(32, 8), 0, stream>>>(lf, lf_t);
  k_convert_w<<<12544, 256, 0, stream>>>((const float4*)roiW, (ushort4*)Wb);
  k_roi<<<576, 512, 0, stream>>>(lf_t, pred, flat);
  // NOTE: partials aliases lf_t's region; k_roi (last reader of lf_t) is
  // stream-ordered before k_gemm (first writer of partials).
  k_gemm<<<dim3(4, 5, KSPLIT), 256, 0, stream>>>(flat, Wb, partials);
  k_reduce<<<(M_ROWS * HIDN) / 256, 256, 0, stream>>>(partials, roiB, feats);
  k_heads<<<1160, 256, 0, stream>>>(feats, pred, cW, cb, pW, pb, lW, lb, gW, gb,
                                    lidx, gidx, out);
}

// Round 2
// 227.437 us; speedup vs baseline: 1.8311x; 1.8311x over previous
//
#include <hip/hip_runtime.h>

typedef unsigned short u16;
typedef __attribute__((ext_vector_type(8))) short short8;
typedef __attribute__((ext_vector_type(8))) unsigned short ushort8_t;
typedef __attribute__((ext_vector_type(4))) float f32x4;

#define BATCH   16
#define CCH     512
#define NBOX    36
#define SS      26
#define INDIM   25088   // 512*49
#define HIDN    512
#define M_ROWS  576     // BATCH*NBOX
#define KSPLIT  28
#define KITERS  14      // per split, BK=64 -> 28*14*64 = 25088

__device__ __forceinline__ u16 f2bf(float f) {
  unsigned u = __float_as_uint(f);
  u += 0x7FFF + ((u >> 16) & 1);   // RNE
  return (u16)(u >> 16);
}
__device__ __forceinline__ float bf2f(u16 h) {
  return __uint_as_float(((unsigned)h) << 16);
}

typedef __attribute__((address_space(3))) void* as3_ptr;
typedef const __attribute__((address_space(1))) void* as1_cptr;
__device__ __forceinline__ void gload_lds16(const void* g, void* l) {
  __builtin_amdgcn_global_load_lds((as1_cptr)g, (as3_ptr)l, 16, 0, 0);
}

// ---------------- kernel 1: transpose lf (B,C,H,W) f32 -> (B,HW,C) bf16 ----
__global__ __launch_bounds__(256) void k_transpose_lf(const float* __restrict__ in,
                                                      u16* __restrict__ out) {
  __shared__ float t[32][33];
  int b = blockIdx.z, ct = blockIdx.y, pt = blockIdx.x;
  int tx = threadIdx.x, ty = threadIdx.y;
#pragma unroll
  for (int i = 0; i < 4; ++i) {
    int c = ct * 32 + ty + i * 8;
    int p = pt * 32 + tx;
    t[ty + i * 8][tx] = in[((size_t)b * CCH + c) * 1024 + p];
  }
  __syncthreads();
#pragma unroll
  for (int i = 0; i < 4; ++i) {
    int p = pt * 32 + ty + i * 8;
    int c = ct * 32 + tx;
    out[((size_t)b * 1024 + p) * CCH + c] = f2bf(t[tx][ty + i * 8]);
  }
}

// ---------------- kernel 2: roi_fc_W f32 -> bf16 ---------------------------
__global__ __launch_bounds__(256) void k_convert_w(const float4* __restrict__ in,
                                                   ushort4* __restrict__ out) {
  int i = blockIdx.x * 256 + threadIdx.x;   // grid sized exactly
  float4 v = in[i];
  ushort4 o;
  o.x = f2bf(v.x); o.y = f2bf(v.y); o.z = f2bf(v.z); o.w = f2bf(v.w);
  out[i] = o;
}

// ---------------- kernel 3: ROI align -> flat (576, 25088) bf16 ------------
// v2: thread = (cg = tid&63 -> 8 contiguous channels, pg = tid>>6 -> pixel
// stripe). 16B ushort8 loads (1 KB/wave/tap), 8-float acc per pixel that dies
// each iteration -> no VGPR spill (v1 spilled ~108 MB of scratch to HBM).
__global__ __launch_bounds__(512) void k_roi(const u16* __restrict__ lf_t,
                                             const float* __restrict__ pred,
                                             u16* __restrict__ flat) {
  __shared__ int   s_ylo[14], s_yhi[14], s_xlo[14], s_xhi[14];
  __shared__ float s_wyl[14], s_wyh[14], s_wxl[14], s_wxh[14];
  __shared__ u16   s_out[INDIM];   // 50176 B

  int blk = blockIdx.x;
  int b = blk / NBOX, n = blk % NBOX;
  int t = threadIdx.x;

  if (t < 28) {
    bool isY = t < 14;
    int j = isY ? t : t - 14;
    float c0, c1, c2, c3;
    if (n < SS) {
      const float* p = pred + ((size_t)(b * SS + n)) * 4;
      c0 = p[0]; c1 = p[1]; c2 = p[2]; c3 = p[3];
    } else { c0 = 0.f; c1 = 0.f; c2 = 1.f; c3 = 1.f; }
    float lo1 = (isY ? c1 : c0) * 32.f;
    float hi1 = (isY ? c3 : c2) * 32.f;
    float sz = fmaxf(hi1 - lo1, 1.f);
    float bs = sz * (1.f / 7.f);
    float off = (float)(j >> 1) + 0.25f + 0.5f * (float)(j & 1);
    float pos = lo1 + off * bs;
    bool valid = (pos > -1.f) && (pos < 32.f);
    float tc = fminf(fmaxf(pos, 0.f), 31.f);
    int lo = (int)floorf(tc);
    int hi = min(lo + 1, 31);
    float fr = tc - (float)lo;
    float wl = valid ? (1.f - fr) : 0.f;
    float wh = valid ? fr : 0.f;
    if (isY) { s_ylo[j] = lo; s_yhi[j] = hi; s_wyl[j] = wl; s_wyh[j] = wh; }
    else     { s_xlo[j] = lo; s_xhi[j] = hi; s_wxl[j] = wl; s_wxh[j] = wh; }
  }
  __syncthreads();

  int cg = t & 63;          // channel group: channels cg*8 .. cg*8+7
  int pg = t >> 6;          // pixel stripe: pixels pg, pg+8, ...
  const u16* base = lf_t + (size_t)b * 1024 * CCH + cg * 8;

  for (int p = pg; p < 49; p += 8) {
    int py = p / 7, px = p % 7;
    float a0 = 0.f, a1 = 0.f, a2 = 0.f, a3 = 0.f;
    float a4 = 0.f, a5 = 0.f, a6 = 0.f, a7 = 0.f;
#pragma unroll
    for (int sy = 0; sy < 2; ++sy) {
      int jy = 2 * py + sy;
      const u16* rlo = base + s_ylo[jy] * 32 * CCH;
      const u16* rhi = base + s_yhi[jy] * 32 * CCH;
      float wyl = s_wyl[jy], wyh = s_wyh[jy];
#pragma unroll
      for (int sx = 0; sx < 2; ++sx) {
        int jx = 2 * px + sx;
        int xl = s_xlo[jx] * CCH, xh = s_xhi[jx] * CCH;
        float wll = wyl * s_wxl[jx], wlh = wyl * s_wxh[jx];
        float whl = wyh * s_wxl[jx], whh = wyh * s_wxh[jx];
        ushort8_t vll = *(const ushort8_t*)(rlo + xl);
        ushort8_t vlh = *(const ushort8_t*)(rlo + xh);
        ushort8_t vhl = *(const ushort8_t*)(rhi + xl);
        ushort8_t vhh = *(const ushort8_t*)(rhi + xh);
        a0 += wll * bf2f(vll[0]) + wlh * bf2f(vlh[0]) + whl * bf2f(vhl[0]) + whh * bf2f(vhh[0]);
        a1 += wll * bf2f(vll[1]) + wlh * bf2f(vlh[1]) + whl * bf2f(vhl[1]) + whh * bf2f(vhh[1]);
        a2 += wll * bf2f(vll[2]) + wlh * bf2f(vlh[2]) + whl * bf2f(vhl[2]) + whh * bf2f(vhh[2]);
        a3 += wll * bf2f(vll[3]) + wlh * bf2f(vlh[3]) + whl * bf2f(vhl[3]) + whh * bf2f(vhh[3]);
        a4 += wll * bf2f(vll[4]) + wlh * bf2f(vlh[4]) + whl * bf2f(vhl[4]) + whh * bf2f(vhh[4]);
        a5 += wll * bf2f(vll[5]) + wlh * bf2f(vlh[5]) + whl * bf2f(vhl[5]) + whh * bf2f(vhh[5]);
        a6 += wll * bf2f(vll[6]) + wlh * bf2f(vlh[6]) + whl * bf2f(vhl[6]) + whh * bf2f(vhh[6]);
        a7 += wll * bf2f(vll[7]) + wlh * bf2f(vlh[7]) + whl * bf2f(vhl[7]) + whh * bf2f(vhh[7]);
      }
    }
    int c0i = cg * 8;
    s_out[(c0i + 0) * 49 + p] = f2bf(a0 * 0.25f);
    s_out[(c0i + 1) * 49 + p] = f2bf(a1 * 0.25f);
    s_out[(c0i + 2) * 49 + p] = f2bf(a2 * 0.25f);
    s_out[(c0i + 3) * 49 + p] = f2bf(a3 * 0.25f);
    s_out[(c0i + 4) * 49 + p] = f2bf(a4 * 0.25f);
    s_out[(c0i + 5) * 49 + p] = f2bf(a5 * 0.25f);
    s_out[(c0i + 6) * 49 + p] = f2bf(a6 * 0.25f);
    s_out[(c0i + 7) * 49 + p] = f2bf(a7 * 0.25f);
  }
  __syncthreads();

  uint4* dst = (uint4*)(flat + (size_t)blk * INDIM);
  const uint4* src = (const uint4*)s_out;
  for (int i = t; i < INDIM / 8; i += 512) dst[i] = src[i];
}

// ---------------- kernel 4: GEMM 576(+pad)x512xK, split-K, bf16 MFMA -------
__global__ __launch_bounds__(256) void k_gemm(const u16* __restrict__ flat,
                                              const u16* __restrict__ Wb,
                                              float* __restrict__ partials) {
  __shared__ u16 As[128 * 64];
  __shared__ u16 Bs[128 * 64];

  int tid = threadIdx.x;
  int wave = tid >> 6, lane = tid & 63;
  int wm = wave >> 1, wn = wave & 1;
  int quad = lane >> 4, r = lane & 15;

  int tileM0 = blockIdx.y * 128;
  int tileN0 = blockIdx.x * 128;
  int kbase = blockIdx.z * (KITERS * 64);

  f32x4 acc[4][4];
#pragma unroll
  for (int mi = 0; mi < 4; ++mi)
#pragma unroll
    for (int ni = 0; ni < 4; ++ni) acc[mi][ni] = (f32x4){0.f, 0.f, 0.f, 0.f};

  for (int kt = 0; kt < KITERS; ++kt) {
    int k0 = kbase + kt * 64;
    // stage A and B (16B global_load_lds, lane-contiguous LDS dest)
#pragma unroll
    for (int t = 0; t < 4; ++t) {
      int chunk = (wave * 4 + t) * 64 + lane;
      int row = chunk >> 3;
      int col = (chunk & 7) << 3;
      int grow = min(tileM0 + row, M_ROWS - 1);   // clamp M tail
      gload_lds16(flat + (size_t)grow * INDIM + k0 + col,
                  &As[(wave * 4 + t) * 512]);
      int nrow = tileN0 + row;
      gload_lds16(Wb + (size_t)nrow * INDIM + k0 + col,
                  &Bs[(wave * 4 + t) * 512]);
    }
    __syncthreads();

#pragma unroll
    for (int kk = 0; kk < 64; kk += 32) {
      short8 af[4], bfr[4];
#pragma unroll
      for (int mi = 0; mi < 4; ++mi)
        af[mi] = *(const short8*)&As[(wm * 64 + mi * 16 + r) * 64 + kk + quad * 8];
#pragma unroll
      for (int ni = 0; ni < 4; ++ni)
        bfr[ni] = *(const short8*)&Bs[(wn * 64 + ni * 16 + r) * 64 + kk + quad * 8];
#pragma unroll
      for (int mi = 0; mi < 4; ++mi)
#pragma unroll
        for (int ni = 0; ni < 4; ++ni)
          acc[mi][ni] = __builtin_amdgcn_mfma_f32_16x16x32_bf16(
              af[mi], bfr[ni], acc[mi][ni], 0, 0, 0);
    }
    __syncthreads();
  }

  float* part = partials + (size_t)blockIdx.z * (M_ROWS * HIDN);
#pragma unroll
  for (int mi = 0; mi < 4; ++mi)
#pragma unroll
    for (int ni = 0; ni < 4; ++ni) {
      int row0 = tileM0 + wm * 64 + mi * 16 + quad * 4;
      int col = tileN0 + wn * 64 + ni * 16 + r;
#pragma unroll
      for (int reg = 0; reg < 4; ++reg) {
        int row = row0 + reg;
        if (row < M_ROWS) part[(size_t)row * HIDN + col] = acc[mi][ni][reg];
      }
    }
}

// ---------------- kernel 5: reduce split-K + bias + relu -> feats f32 ------
__global__ __launch_bounds__(256) void k_reduce(const float* __restrict__ partials,
                                                const float* __restrict__ bias,
                                                float* __restrict__ feats) {
  int gid = blockIdx.x * 256 + threadIdx.x;   // < 576*512
  int h = gid & (HIDN - 1);
  float s = 0.f;
#pragma unroll
  for (int k = 0; k < KSPLIT; ++k) s += partials[(size_t)k * (M_ROWS * HIDN) + gid];
  s += bias[h];
  feats[gid] = fmaxf(s, 0.f);
}

// ---------------- kernel 6: all heads, one wave per output dot -------------
__device__ __forceinline__ float wave_red(float s) {
#pragma unroll
  for (int off = 32; off > 0; off >>= 1) s += __shfl_down(s, off);
  return s;
}

__global__ __launch_bounds__(256) void k_heads(const float* __restrict__ feats,
                                               const float* __restrict__ pred,
                                               const float* __restrict__ cW,
                                               const float* __restrict__ cb,
                                               const float* __restrict__ pW,
                                               const float* __restrict__ pb,
                                               const float* __restrict__ lW,
                                               const float* __restrict__ lb,
                                               const float* __restrict__ gW,
                                               const float* __restrict__ gb,
                                               const int* __restrict__ lidx,
                                               const int* __restrict__ gidx,
                                               float* __restrict__ out) {
  int wid = blockIdx.x * 4 + (threadIdx.x >> 6);   // 0..4639
  int lane = threadIdx.x & 63;
  float sum = 0.f;

  if (wid < 1664) {                 // refined (B,26,4)
    int b = wid / 104, rr = wid % 104, s = rr >> 2, o = rr & 3;
    const float* f = feats + (size_t)(b * NBOX + s) * HIDN;
    const float* w = cW + (size_t)(s * 4 + o) * HIDN;
#pragma unroll
    for (int i = 0; i < 8; ++i) sum += f[lane + i * 64] * w[lane + i * 64];
    sum = wave_red(sum);
    if (lane == 0) {
      const float* p = pred + (size_t)(b * SS + s) * 4;
      float wdt = p[2] - p[0], hgt = p[3] - p[1];
      float whv = (o & 1) ? hgt : wdt;
      out[wid] = p[o] + (sum + cb[s * 4 + o]) * whv;
    }
  } else if (wid < 2080) {          // presence (B,26)
    int i = wid - 1664;
    int b = i / 26, s = i % 26;
    const float* f = feats + (size_t)(b * NBOX + s) * HIDN;
    const float* w = pW + (size_t)s * HIDN;
#pragma unroll
    for (int k = 0; k < 8; ++k) sum += f[lane + k * 64] * w[lane + k * 64];
    sum = wave_red(sum);
    if (lane == 0) out[1664 + i] = sum + pb[s];
  } else if (wid < 3616) {          // loc (B,12,8)
    int i = wid - 2080;
    int b = i / 96, rr = i % 96, l = rr >> 3, o = rr & 7;
    const float* f = feats + (size_t)(b * NBOX + lidx[l]) * HIDN;
    const float* w = lW + (size_t)(l * 8 + o) * HIDN;
#pragma unroll
    for (int k = 0; k < 8; ++k) sum += f[lane + k * 64] * w[lane + k * 64];
    sum = wave_red(sum);
    if (lane == 0) out[2080 + b * 160 + rr] = sum + lb[l * 8 + o];
  } else {                          // grp (B,4,16), K = 6*512
    int i = wid - 3616;
    int b = i / 64, rr = i % 64, g = rr >> 4, o = rr & 15;
    const float* w = gW + (size_t)(g * 16 + o) * 3072;
#pragma unroll
    for (int jj = 0; jj < 6; ++jj) {
      const float* f = feats + (size_t)(b * NBOX + gidx[g * 6 + jj]) * HIDN;
      const float* wj = w + jj * 512;
#pragma unroll
      for (int k = 0; k < 8; ++k) sum += f[lane + k * 64] * wj[lane + k * 64];
    }
    sum = wave_red(sum);
    if (lane == 0) out[2080 + b * 160 + 96 + rr] = sum + gb[g * 16 + o];
  }
}

// ---------------------------------------------------------------------------
extern "C" void kernel_launch(void* const* d_in, const int* in_sizes, int n_in,
                              void* d_out, int out_size, void* d_ws, size_t ws_size,
                              hipStream_t stream) {
  const float* lf      = (const float*)d_in[0];
  const float* pred    = (const float*)d_in[1];
  const float* roiW    = (const float*)d_in[2];
  const float* roiB    = (const float*)d_in[3];
  const float* cW      = (const float*)d_in[4];
  const float* cb      = (const float*)d_in[5];
  const float* pW      = (const float*)d_in[6];
  const float* pb      = (const float*)d_in[7];
  const float* lW      = (const float*)d_in[8];
  const float* lb      = (const float*)d_in[9];
  const float* gW      = (const float*)d_in[10];
  const float* gb      = (const float*)d_in[11];
  const int*   lidx    = (const int*)d_in[12];
  const int*   gidx    = (const int*)d_in[13];
  float* out = (float*)d_out;

  char* ws = (char*)d_ws;
  // region 0: lf_t (16.8 MB) then reused by partials (33.0 MB) after k_roi
  u16*   lf_t     = (u16*)ws;
  float* partials = (float*)ws;
  u16*   Wb   = (u16*)(ws + 33030144);                 // 25,690,112 B
  u16*   flat = (u16*)(ws + 33030144 + 25690112);      // 28,901,376 B
  float* feats = (float*)(ws + 33030144 + 25690112 + 28901376); // 1,179,648 B

  k_transpose_lf<<<dim3(32, 16, 16), dim3(32, 8), 0, stream>>>(lf, lf_t);
  k_convert_w<<<12544, 256, 0, stream>>>((const float4*)roiW, (ushort4*)Wb);
  k_roi<<<576, 512, 0, stream>>>(lf_t, pred, flat);
  // NOTE: partials aliases lf_t's region; k_roi (last reader of lf_t) is
  // stream-ordered before k_gemm (first writer of partials).
  k_gemm<<<dim3(4, 5, KSPLIT), 256, 0, stream>>>(flat, Wb, partials);
  k_reduce<<<(M_ROWS * HIDN) / 256, 256, 0, stream>>>(partials, roiB, feats);
  k_heads<<<1160, 256, 0, stream>>>(feats, pred, cW, cb, pW, pb, lW, lb, gW, gb,
                                    lidx, gidx, out);
}